// Round 1
// baseline (217.787 us; speedup 1.0000x reference)
//
#include <hip/hip_runtime.h>

#define NB 4
#define NT 2048
#define NE 512
#define NH 8
#define ND 64
#define BH (NB*NH)

typedef __attribute__((ext_vector_type(8))) short short8;
typedef __attribute__((ext_vector_type(4))) short short4v;
typedef __attribute__((ext_vector_type(4))) float f32x4;
typedef __attribute__((ext_vector_type(2))) float f32x2;

__device__ __forceinline__ f32x4 mfma16(short8 a, short8 b, f32x4 c){
  return __builtin_amdgcn_mfma_f32_16x16x32_bf16(a, b, c, 0, 0, 0);
}
__device__ __forceinline__ short f2b(float f){
  union { float f; unsigned u; } v; v.f = f;
  unsigned r = v.u + 0x7FFFu + ((v.u >> 16) & 1u);
  return (short)(r >> 16);
}
__device__ __forceinline__ void gld16(const void* g, void* l){
  __builtin_amdgcn_global_load_lds((const __attribute__((address_space(1))) void*)g,
                                   (__attribute__((address_space(3))) void*)l, 16, 0, 0);
}

// ---------------- pack x (fp32 -> bf16) ----------------
__global__ __launch_bounds__(256) void pack_x_k(const float* __restrict__ x, short* __restrict__ xb){
  int i = blockIdx.x*256 + threadIdx.x;
  f32x4 a = ((const f32x4*)x)[2*i];
  f32x4 b = ((const f32x4*)x)[2*i+1];
  short8 o;
  o[0]=f2b(a[0]); o[1]=f2b(a[1]); o[2]=f2b(a[2]); o[3]=f2b(a[3]);
  o[4]=f2b(b[0]); o[5]=f2b(b[1]); o[6]=f2b(b[2]); o[7]=f2b(b[3]);
  ((short8*)xb)[i] = o;
}

// ---------------- pack W transposed (fp32 [e][j] -> bf16 [j][e]) ----------------
__global__ __launch_bounds__(256) void pack_wt_k(const float* __restrict__ Wq, const float* __restrict__ Wk,
                                                 const float* __restrict__ Wv, const float* __restrict__ Wo,
                                                 short* __restrict__ Wt){
  const float* W = blockIdx.z==0?Wq: blockIdx.z==1?Wk: blockIdx.z==2?Wv:Wo;
  short* out = Wt + (size_t)blockIdx.z*NE*NE;
  __shared__ float t[32][33];
  int tx = threadIdx.x & 31, ty = threadIdx.x >> 5;
  int j0 = blockIdx.x*32, e0 = blockIdx.y*32;
#pragma unroll
  for (int r = 0; r < 4; ++r)
    t[ty*4+r][tx] = W[(size_t)(e0+ty*4+r)*NE + j0+tx];
  __syncthreads();
#pragma unroll
  for (int r = 0; r < 4; ++r)
    out[(size_t)(j0+ty*4+r)*NE + e0+tx] = f2b(t[tx][ty*4+r]);
}

// ---------------- QKV projection GEMM: (8192x512)@(512x512)+bias -> (B,H,T,D) bf16 ----------------
__global__ __launch_bounds__(256) void gemm_qkv_k(const short* __restrict__ xb, const short* __restrict__ Wt,
                                                  const float* __restrict__ bq, const float* __restrict__ bk,
                                                  const float* __restrict__ bv,
                                                  short* __restrict__ Q, short* __restrict__ K, short* __restrict__ V){
  int z = blockIdx.z;
  const short* Bm = Wt + (size_t)z*NE*NE;
  const float* bias = z==0?bq: z==1?bk:bv;
  short* out = z==0?Q: z==1?K:V;
  float scale = (z==0) ? 0.125f : 1.0f;   // fold 1/sqrt(D) into Q

  __shared__ short As[128*32];
  __shared__ short Bs[128*32];
  int tid = threadIdx.x, lane = tid & 63, wid = tid >> 6;
  int m0 = blockIdx.y*128, n0 = blockIdx.x*128;
  int wm = wid >> 1, wn = wid & 1;
  int sr = lane >> 2, sg = lane & 3;     // staging: 16 rows/instr, 4 chunks/row
  int fr = lane & 15, fg = lane >> 4;

  f32x4 acc[4][4] = {};

  for (int kt = 0; kt < 16; ++kt){
    int k0 = kt*32;
    {
      int ii0 = wid*2, ii1 = wid*2+1;
      int r0 = ii0*16 + sr, r1 = ii1*16 + sr;
      gld16(xb + (size_t)(m0 + r0)*NE + k0 + ((sg ^ (r0&3))<<3), (short*)As + ii0*512);
      gld16(xb + (size_t)(m0 + r1)*NE + k0 + ((sg ^ (r1&3))<<3), (short*)As + ii1*512);
      gld16(Bm + (size_t)(n0 + r0)*NE + k0 + ((sg ^ (r0&3))<<3), (short*)Bs + ii0*512);
      gld16(Bm + (size_t)(n0 + r1)*NE + k0 + ((sg ^ (r1&3))<<3), (short*)Bs + ii1*512);
    }
    __syncthreads();
    short8 af[4], bf[4];
#pragma unroll
    for (int m = 0; m < 4; ++m){
      int row = wm*64 + m*16 + fr;
      af[m] = *(const short8*)&As[row*32 + ((fg ^ (row&3))<<3)];
    }
#pragma unroll
    for (int n = 0; n < 4; ++n){
      int row = wn*64 + n*16 + fr;
      bf[n] = *(const short8*)&Bs[row*32 + ((fg ^ (row&3))<<3)];
    }
#pragma unroll
    for (int m = 0; m < 4; ++m)
#pragma unroll
      for (int n = 0; n < 4; ++n)
        acc[m][n] = mfma16(af[m], bf[n], acc[m][n]);
    __syncthreads();
  }
#pragma unroll
  for (int m = 0; m < 4; ++m)
#pragma unroll
    for (int n = 0; n < 4; ++n)
#pragma unroll
      for (int i = 0; i < 4; ++i){
        int row = m0 + wm*64 + m*16 + fg*4 + i;
        int col = n0 + wn*64 + n*16 + fr;
        float v = (acc[m][n][i] + bias[col]) * scale;
        int b = row >> 11, t = row & (NT-1), h = col >> 6, d = col & 63;
        out[(((size_t)(b*NH + h)*NT + t)<<6) + d] = f2b(v);
      }
}

// ---------------- pass 1: per-k column stats (softmax over q axis) ----------------
__global__ __launch_bounds__(256) void attn_stats_k(const short* __restrict__ Q, const short* __restrict__ K,
                                                    f32x2* __restrict__ stats){
  int bh = blockIdx.y;
  const short* Qh = Q + (size_t)bh*NT*ND;
  const short* Kh = K + (size_t)bh*NT*ND;
  int kbase = blockIdx.x*128;
  __shared__ short Ks[128*64];
  __shared__ short Qs[64*64];
  int tid = threadIdx.x, lane = tid&63, wid = tid>>6;
  int sr = lane >> 3, sg = lane & 7;    // staging: 8 rows/instr, 8 chunks/row
  int fr = lane & 15, fg = lane >> 4;

  // stage K tile once (swizzled source chunks)
  for (int ii = wid*4; ii < wid*4+4; ++ii){
    int r = ii*8 + sr;
    gld16(Kh + (size_t)(kbase + r)*ND + ((sg ^ (r&7))<<3), (short*)Ks + ii*512);
  }

  float rm[2][4], rl[2][4];
#pragma unroll
  for (int a = 0; a < 2; ++a)
#pragma unroll
    for (int i = 0; i < 4; ++i){ rm[a][i] = -1e30f; rl[a][i] = 0.f; }

  for (int qt = 0; qt < 32; ++qt){
    for (int ii = wid*2; ii < wid*2+2; ++ii){
      int r = ii*8 + sr;
      gld16(Qh + (size_t)(qt*64 + r)*ND + ((sg ^ (r&7))<<3), (short*)Qs + ii*512);
    }
    __syncthreads();
    short8 ak[2][2], bq8[4][2];
#pragma unroll
    for (int rf = 0; rf < 2; ++rf){
      int row = wid*32 + rf*16 + fr;
#pragma unroll
      for (int dh = 0; dh < 2; ++dh)
        ak[rf][dh] = *(const short8*)&Ks[row*64 + (((dh*4+fg) ^ (row&7))<<3)];
    }
#pragma unroll
    for (int qf = 0; qf < 4; ++qf){
      int row = qf*16 + fr;
#pragma unroll
      for (int dh = 0; dh < 2; ++dh)
        bq8[qf][dh] = *(const short8*)&Qs[row*64 + (((dh*4+fg) ^ (row&7))<<3)];
    }
    f32x4 s[2][4];
#pragma unroll
    for (int rf = 0; rf < 2; ++rf)
#pragma unroll
      for (int qf = 0; qf < 4; ++qf){
        f32x4 c = {};
        c = mfma16(ak[rf][0], bq8[qf][0], c);
        c = mfma16(ak[rf][1], bq8[qf][1], c);
        s[rf][qf] = c;
      }
#pragma unroll
    for (int rf = 0; rf < 2; ++rf)
#pragma unroll
      for (int i = 0; i < 4; ++i){
        float tm = fmaxf(fmaxf(s[rf][0][i], s[rf][1][i]), fmaxf(s[rf][2][i], s[rf][3][i]));
        tm = fmaxf(tm, __shfl_xor(tm, 1));
        tm = fmaxf(tm, __shfl_xor(tm, 2));
        tm = fmaxf(tm, __shfl_xor(tm, 4));
        tm = fmaxf(tm, __shfl_xor(tm, 8));
        float nm = fmaxf(rm[rf][i], tm);
        float se = __expf(s[rf][0][i]-nm) + __expf(s[rf][1][i]-nm)
                 + __expf(s[rf][2][i]-nm) + __expf(s[rf][3][i]-nm);
        se += __shfl_xor(se, 1); se += __shfl_xor(se, 2);
        se += __shfl_xor(se, 4); se += __shfl_xor(se, 8);
        rl[rf][i] = rl[rf][i]*__expf(rm[rf][i]-nm) + se;
        rm[rf][i] = nm;
      }
    __syncthreads();
  }
  if (fr == 0){
#pragma unroll
    for (int rf = 0; rf < 2; ++rf)
#pragma unroll
      for (int i = 0; i < 4; ++i){
        int k = kbase + wid*32 + rf*16 + fg*4 + i;
        f32x2 st; st[0] = rm[rf][i]; st[1] = 1.0f / rl[rf][i];
        stats[(size_t)bh*NT + k] = st;
      }
  }
}

// ---------------- pass 2: recompute S, normalize, PV, scrambled write ----------------
__global__ __launch_bounds__(256) void attn_out_k(const short* __restrict__ Q, const short* __restrict__ K,
                                                  const short* __restrict__ V, const f32x2* __restrict__ stats,
                                                  short* __restrict__ out2){
  int bh = blockIdx.y, b = bh >> 3, h = bh & 7;
  const short* Qh = Q + (size_t)bh*NT*ND;
  const short* Kh = K + (size_t)bh*NT*ND;
  const short* Vh = V + (size_t)bh*NT*ND;
  const f32x2* sh = stats + (size_t)bh*NT;
  int q0 = blockIdx.x*128;
  __shared__ short Qs[128*64];
  __shared__ short Ks[64*64];
  __shared__ short Vt[64*72];      // transposed V, padded rows (72 shorts = 144 B)
  __shared__ short Ps[128*64];     // P, row-XOR-swizzled chunks
  int tid = threadIdx.x, lane = tid&63, wid = tid>>6;
  int sr = lane>>3, sg = lane&7;
  int fr = lane&15, fg = lane>>4;
  int vr = tid>>2, vc = (tid&3)*16;  // V transpose mapping

  for (int ii = wid*4; ii < wid*4+4; ++ii){
    int r = ii*8 + sr;
    gld16(Qh + (size_t)(q0 + r)*ND + ((sg ^ (r&7))<<3), (short*)Qs + ii*512);
  }

  f32x4 oacc[2][4] = {};

  for (int kt = 0; kt < 32; ++kt){
    for (int ii = wid*2; ii < wid*2+2; ++ii){
      int r = ii*8 + sr;
      gld16(Kh + (size_t)(kt*64 + r)*ND + ((sg ^ (r&7))<<3), (short*)Ks + ii*512);
    }
    { // V transpose into LDS
      short8 v0 = *(const short8*)&Vh[(size_t)(kt*64 + vr)*ND + vc];
      short8 v1 = *(const short8*)&Vh[(size_t)(kt*64 + vr)*ND + vc + 8];
#pragma unroll
      for (int j = 0; j < 8; ++j) Vt[(vc + j)*72 + vr] = v0[j];
#pragma unroll
      for (int j = 0; j < 8; ++j) Vt[(vc + 8 + j)*72 + vr] = v1[j];
    }
    __syncthreads();

    // S^T frags (rows=k, cols=q), wave owns q cols [wid*32, wid*32+32)
    short8 ak[4][2], bq8[2][2];
#pragma unroll
    for (int rf = 0; rf < 4; ++rf){
      int row = rf*16 + fr;
#pragma unroll
      for (int dh = 0; dh < 2; ++dh)
        ak[rf][dh] = *(const short8*)&Ks[row*64 + (((dh*4+fg) ^ (row&7))<<3)];
    }
#pragma unroll
    for (int qf = 0; qf < 2; ++qf){
      int row = wid*32 + qf*16 + fr;
#pragma unroll
      for (int dh = 0; dh < 2; ++dh)
        bq8[qf][dh] = *(const short8*)&Qs[row*64 + (((dh*4+fg) ^ (row&7))<<3)];
    }
#pragma unroll
    for (int rf = 0; rf < 4; ++rf){
      f32x2 ml[4];
#pragma unroll
      for (int i = 0; i < 4; ++i)
        ml[i] = sh[kt*64 + rf*16 + fg*4 + i];
#pragma unroll
      for (int qf = 0; qf < 2; ++qf){
        f32x4 c = {};
        c = mfma16(ak[rf][0], bq8[qf][0], c);
        c = mfma16(ak[rf][1], bq8[qf][1], c);
        short4v p4;
#pragma unroll
        for (int i = 0; i < 4; ++i)
          p4[i] = f2b(__expf(c[i] - ml[i][0]) * ml[i][1]);
        int q = wid*32 + qf*16 + fr;
        int kk4 = rf*16 + fg*4;
        int chunk = kk4 >> 3;
        int off = (kk4 & 7) << 1;
        *(short4v*)((char*)Ps + q*128 + (((chunk ^ (q&7))<<4) | off)) = p4;
      }
    }
    // PV: O[q][d] += P[q][k] * V[k][d]
    short8 pa[2][2], vb[4][2];
#pragma unroll
    for (int m = 0; m < 2; ++m){
      int q = wid*32 + m*16 + fr;
#pragma unroll
      for (int kk = 0; kk < 2; ++kk){
        int chunk = kk*4 + fg;
        pa[m][kk] = *(const short8*)((const char*)Ps + q*128 + ((chunk ^ (q&7))<<4));
      }
    }
#pragma unroll
    for (int n = 0; n < 4; ++n){
      int d = n*16 + fr;
#pragma unroll
      for (int kk = 0; kk < 2; ++kk)
        vb[n][kk] = *(const short8*)&Vt[d*72 + kk*32 + fg*8];
    }
#pragma unroll
    for (int m = 0; m < 2; ++m)
#pragma unroll
      for (int n = 0; n < 4; ++n){
        oacc[m][n] = mfma16(pa[m][0], vb[n][0], oacc[m][n]);
        oacc[m][n] = mfma16(pa[m][1], vb[n][1], oacc[m][n]);
      }
    __syncthreads();
  }

  // scrambled reshape write: (B,H,T,D) -> (B, T', H*D) with r=h*256+t/8, e=64*(t%8)+d
#pragma unroll
  for (int m = 0; m < 2; ++m)
#pragma unroll
    for (int n = 0; n < 4; ++n)
#pragma unroll
      for (int i = 0; i < 4; ++i){
        int t = q0 + wid*32 + m*16 + fg*4 + i;
        int d = n*16 + fr;
        int r = h*256 + (t>>3);
        int e = ((t&7)<<6) + d;
        out2[((size_t)(b*NT + r)<<9) + e] = f2b(oacc[m][n][i]);
      }
}

// ---------------- output projection: out2 @ Wo + bo -> fp32 ----------------
__global__ __launch_bounds__(256) void gemm_out_k(const short* __restrict__ A, const short* __restrict__ Bm,
                                                  const float* __restrict__ bo, float* __restrict__ out){
  __shared__ short As[128*32];
  __shared__ short Bs[128*32];
  int tid = threadIdx.x, lane = tid & 63, wid = tid >> 6;
  int m0 = blockIdx.y*128, n0 = blockIdx.x*128;
  int wm = wid >> 1, wn = wid & 1;
  int sr = lane >> 2, sg = lane & 3;
  int fr = lane & 15, fg = lane >> 4;

  f32x4 acc[4][4] = {};

  for (int kt = 0; kt < 16; ++kt){
    int k0 = kt*32;
    {
      int ii0 = wid*2, ii1 = wid*2+1;
      int r0 = ii0*16 + sr, r1 = ii1*16 + sr;
      gld16(A  + (size_t)(m0 + r0)*NE + k0 + ((sg ^ (r0&3))<<3), (short*)As + ii0*512);
      gld16(A  + (size_t)(m0 + r1)*NE + k0 + ((sg ^ (r1&3))<<3), (short*)As + ii1*512);
      gld16(Bm + (size_t)(n0 + r0)*NE + k0 + ((sg ^ (r0&3))<<3), (short*)Bs + ii0*512);
      gld16(Bm + (size_t)(n0 + r1)*NE + k0 + ((sg ^ (r1&3))<<3), (short*)Bs + ii1*512);
    }
    __syncthreads();
    short8 af[4], bf[4];
#pragma unroll
    for (int m = 0; m < 4; ++m){
      int row = wm*64 + m*16 + fr;
      af[m] = *(const short8*)&As[row*32 + ((fg ^ (row&3))<<3)];
    }
#pragma unroll
    for (int n = 0; n < 4; ++n){
      int row = wn*64 + n*16 + fr;
      bf[n] = *(const short8*)&Bs[row*32 + ((fg ^ (row&3))<<3)];
    }
#pragma unroll
    for (int m = 0; m < 4; ++m)
#pragma unroll
      for (int n = 0; n < 4; ++n)
        acc[m][n] = mfma16(af[m], bf[n], acc[m][n]);
    __syncthreads();
  }
#pragma unroll
  for (int m = 0; m < 4; ++m)
#pragma unroll
    for (int n = 0; n < 4; ++n)
#pragma unroll
      for (int i = 0; i < 4; ++i){
        int row = m0 + wm*64 + m*16 + fg*4 + i;
        int col = n0 + wn*64 + n*16 + fr;
        out[(size_t)row*NE + col] = acc[m][n][i] + bo[col];
      }
}

extern "C" void kernel_launch(void* const* d_in, const int* in_sizes, int n_in,
                              void* d_out, int out_size, void* d_ws, size_t ws_size,
                              hipStream_t stream){
  const float* x  = (const float*)d_in[0];
  const float* Wq = (const float*)d_in[1];
  const float* bq = (const float*)d_in[2];
  const float* Wk = (const float*)d_in[3];
  const float* bk = (const float*)d_in[4];
  const float* Wv = (const float*)d_in[5];
  const float* bv = (const float*)d_in[6];
  const float* Wo = (const float*)d_in[7];
  const float* bo = (const float*)d_in[8];
  float* out = (float*)d_out;

  char* ws = (char*)d_ws;
  size_t off = 0;
  auto alloc = [&](size_t bytes){ void* p = ws + off; off = (off + bytes + 255) & ~(size_t)255; return p; };
  short* xb    = (short*)alloc((size_t)NB*NT*NE*2);
  short* Wt    = (short*)alloc((size_t)4*NE*NE*2);
  short* Qb    = (short*)alloc((size_t)NB*NT*NE*2);
  short* Kb    = (short*)alloc((size_t)NB*NT*NE*2);
  short* Vb    = (short*)alloc((size_t)NB*NT*NE*2);
  f32x2* stats = (f32x2*)alloc((size_t)BH*NT*sizeof(f32x2));
  short* out2  = (short*)alloc((size_t)NB*NT*NE*2);
  (void)ws_size; (void)in_sizes; (void)n_in; (void)out_size;

  pack_x_k<<<dim3((NB*NT*NE/8)/256), dim3(256), 0, stream>>>(x, xb);
  pack_wt_k<<<dim3(NE/32, NE/32, 4), dim3(256), 0, stream>>>(Wq, Wk, Wv, Wo, Wt);
  gemm_qkv_k<<<dim3(NE/128, (NB*NT)/128, 3), dim3(256), 0, stream>>>(xb, Wt, bq, bk, bv, Qb, Kb, Vb);
  attn_stats_k<<<dim3(NT/128, BH), dim3(256), 0, stream>>>(Qb, Kb, stats);
  attn_out_k<<<dim3(NT/128, BH), dim3(256), 0, stream>>>(Qb, Kb, Vb, stats, out2);
  gemm_out_k<<<dim3(NE/128, (NB*NT)/128), dim3(256), 0, stream>>>(out2, Wt + (size_t)3*NE*NE, bo, out);
}